// Round 11
// baseline (576.424 us; speedup 1.0000x reference)
//
#include <hip/hip_runtime.h>

#define NB 2
#define DD 480
#define HH 360
#define WD 32
#define CIN 16
#define COUT 32
#define EPSV 1e-5f
#define NEGS 0.01f
#define NCELLS (NB * DD * HH * WD)

__global__ __launch_bounds__(256) void scatter_grid(const int* __restrict__ coords,
                                                    int* __restrict__ grid, int n) {
    int i = blockIdx.x * 256 + threadIdx.x;
    if (i >= n) return;
    int b = coords[i * 4 + 0];
    int z = coords[i * 4 + 1];
    int y = coords[i * 4 + 2];
    int x = coords[i * 4 + 3];
    grid[(((size_t)b * DD + z) * HH + y) * WD + x] = i;
}

// Cell-order neighbor build: one thread per grid cell. All lanes stream
// grid[c] coalesced (44 MB once); occupied lanes (~1.8%) read their 14
// neighbor cells from L1/L2 (scan order gives locality). Emits the same
// ent/list structures as before. coords not needed.
// ent entries: (k<<24) | j ; list entries: (cnt<<24) | i
__global__ __launch_bounds__(256) void build_nbr_cells(
    const int* __restrict__ grid,
    int* __restrict__ ent133, int* __restrict__ list133,
    int* __restrict__ ent313, int* __restrict__ list313,
    int* __restrict__ lcnt, int n) {
    int c = blockIdx.x * 256 + threadIdx.x;
    if (c >= NCELLS) return;
    int i = grid[c];          // coalesced full-grid stream
    if (i < 0) return;
    int x = c & (WD - 1);
    int r = c >> 5;           // row id = (b*DD+z)*HH + y
    int y = r % HH;
    int z = (r / HH) % DD;
    bool xm = x > 0, xp = x < WD - 1;
    int c1 = 0, c2 = 0;

    // 133: (0,dy,dx), k = (dy+1)*3+(dx+1), skip k=4
    {
        bool rok0 = y > 0, rok2 = y < HH - 1;
#pragma unroll
        for (int t = 0; t < 3; ++t) {
            bool rok = (t == 0) ? rok0 : (t == 2) ? rok2 : true;
            if (!rok) continue;
            int rr = c + (t - 1) * WD;
#pragma unroll
            for (int dx = -1; dx <= 1; ++dx) {
                if (t == 1 && dx == 0) continue;
                if (dx == -1 && !xm) continue;
                if (dx == 1 && !xp) continue;
                int j = grid[rr + dx];
                if (j >= 0) {
                    int k = t * 3 + (dx + 1);
                    ent133[(size_t)c1 * n + i] = (k << 24) | j;
                    ++c1;
                }
            }
        }
    }
    // 313: (dz,0,dx), k = (dz+1)*3+(dx+1), skip k=4
    {
        bool rok0 = z > 0, rok2 = z < DD - 1;
#pragma unroll
        for (int t = 0; t < 3; ++t) {
            bool rok = (t == 0) ? rok0 : (t == 2) ? rok2 : true;
            if (!rok) continue;
            int rr = c + (t - 1) * (WD * HH);
#pragma unroll
            for (int dx = -1; dx <= 1; ++dx) {
                if (t == 1 && dx == 0) continue;
                if (dx == -1 && !xm) continue;
                if (dx == 1 && !xp) continue;
                int j = grid[rr + dx];
                if (j >= 0) {
                    int k = t * 3 + (dx + 1);
                    ent313[(size_t)c2 * n + i] = (k << 24) | j;
                    ++c2;
                }
            }
        }
    }
    if (c1 > 0) { int p = atomicAdd(&lcnt[0], 1); if (p < n) list133[p] = (c1 << 24) | i; }
    if (c2 > 0) { int p = atomicAdd(&lcnt[1], 1); if (p < n) list313[p] = (c2 << 24) | i; }
}

// Fold BN scale into weights once per call; also zeroes lcnt.
// Ws layout (floats): conv1 [9][16][32] @ 0, conv2 [9][32][32] @ 4608,
//                     conv3 [9][16][32] @ 13824, conv4 [9][32][32] @ 18432
__global__ __launch_bounds__(256) void prep_weights(
    const float* __restrict__ W1, const float* __restrict__ W2,
    const float* __restrict__ W3, const float* __restrict__ W4,
    const float* __restrict__ gamma, const float* __restrict__ beta,
    const float* __restrict__ mean, const float* __restrict__ var,
    float* __restrict__ Ws, float* __restrict__ sh, int* __restrict__ lcnt) {
    int t = blockIdx.x * 256 + threadIdx.x;
    if (blockIdx.x == 0 && threadIdx.x < 4) lcnt[threadIdx.x] = 0;
    if (t < 4 * COUT) {
        float s = gamma[t] * rsqrtf(var[t] + EPSV);
        sh[t] = beta[t] - mean[t] * s;
    }
    if (t >= 27648) return;
    const float* src;
    int loc, bn;
    if (t < 4608)       { src = W1; loc = t;         bn = 0; }
    else if (t < 13824) { src = W2; loc = t - 4608;  bn = 1; }
    else if (t < 18432) { src = W3; loc = t - 13824; bn = 2; }
    else                { src = W4; loc = t - 18432; bn = 3; }
    int co = loc & 31;
    float s = gamma[bn * COUT + co] * rsqrtf(var[bn * COUT + co] + EPSV);
    Ws[t] = src[loc] * s;
}

// A: pure dense center-tap pair. No gathers, no divergence.
// Applies lrelu unconditionally; fix_pair inverts it on listed points.
template <int CI>
__global__ __launch_bounds__(256, 4) void center_pair(
    const float* __restrict__ in0, const float* __restrict__ Wc0,
    const float* __restrict__ sh0, float* __restrict__ out0,
    const float* __restrict__ in1, const float* __restrict__ Wc1,
    const float* __restrict__ sh1, float* __restrict__ out1,
    int n, int nblk) {
    __shared__ float Wc[CI * COUT];
    int tid = threadIdx.x;
    bool second = (int)blockIdx.x >= nblk;
    const float* in  = second ? in1 : in0;
    const float* Wg  = second ? Wc1 : Wc0;
    const float* sh  = second ? sh1 : sh0;
    float* out       = second ? out1 : out0;

    {
        const float4* wg4 = (const float4*)Wg;
        float4* wl4 = (float4*)Wc;
        for (int t = tid; t < CI * COUT / 4; t += 256) wl4[t] = wg4[t];
    }
    __syncthreads();

    int ib = second ? (int)blockIdx.x - nblk : (int)blockIdx.x;
    int i = ib * 256 + tid;
    if (i >= n) return;

    float acc[COUT];
    const float4* sh4 = (const float4*)sh;
#pragma unroll
    for (int c4 = 0; c4 < COUT / 4; ++c4) {
        float4 s = sh4[c4];
        acc[c4 * 4 + 0] = s.x; acc[c4 * 4 + 1] = s.y;
        acc[c4 * 4 + 2] = s.z; acc[c4 * 4 + 3] = s.w;
    }

    {
        const float4* f4 = (const float4*)(in + (size_t)i * CI);
#pragma unroll
        for (int q = 0; q < CI / 4; ++q) {
            float4 v = f4[q];
            const float* w = &Wc[q * 4 * COUT];
#pragma unroll
            for (int c4 = 0; c4 < COUT / 4; ++c4) {
                float4 w0 = *(const float4*)&w[0 * COUT + c4 * 4];
                float4 w1 = *(const float4*)&w[1 * COUT + c4 * 4];
                float4 w2 = *(const float4*)&w[2 * COUT + c4 * 4];
                float4 w3 = *(const float4*)&w[3 * COUT + c4 * 4];
                acc[c4 * 4 + 0] += v.x * w0.x + v.y * w1.x + v.z * w2.x + v.w * w3.x;
                acc[c4 * 4 + 1] += v.x * w0.y + v.y * w1.y + v.z * w2.y + v.w * w3.y;
                acc[c4 * 4 + 2] += v.x * w0.z + v.y * w1.z + v.z * w2.z + v.w * w3.z;
                acc[c4 * 4 + 3] += v.x * w0.w + v.y * w1.w + v.z * w2.w + v.w * w3.w;
            }
        }
    }

    float4* o = (float4*)(out + (size_t)i * COUT);
#pragma unroll
    for (int c4 = 0; c4 < COUT / 4; ++c4) {
        float4 r;
        float y0 = acc[4 * c4 + 0], y1 = acc[4 * c4 + 1];
        float y2 = acc[4 * c4 + 2], y3 = acc[4 * c4 + 3];
        r.x = (y0 >= 0.f) ? y0 : NEGS * y0;
        r.y = (y1 >= 0.f) ? y1 : NEGS * y1;
        r.z = (y2 >= 0.f) ? y2 : NEGS * y2;
        r.w = (y3 >= 0.f) ? y3 : NEGS * y3;
        o[c4] = r;
    }
}

// B: fix-up over the compacted list. Invert the lrelu, add extra taps,
// re-apply lrelu. li0/li1 select the lcnt slot for each side (the lists
// are swapped between B13 and B24).
template <int CI>
__global__ __launch_bounds__(256) void fix_pair(
    const float* __restrict__ in0, const int* __restrict__ list0,
    const int* __restrict__ ent0, const float* __restrict__ Ws0,
    float* __restrict__ out0,
    const float* __restrict__ in1, const int* __restrict__ list1,
    const int* __restrict__ ent1, const float* __restrict__ Ws1,
    float* __restrict__ out1,
    const int* __restrict__ lcnt, int li0, int li1, int n, int nblkB) {
    constexpr int WROW = CI * COUT;
    constexpr int WPAD = WROW + 4;
    __shared__ float Wl[9 * WPAD];
    int tid = threadIdx.x;
    bool second = (int)blockIdx.x >= nblkB;
    const float* in   = second ? in1 : in0;
    const int* list   = second ? list1 : list0;
    const int* ent    = second ? ent1 : ent0;
    const float* Ws   = second ? Ws1 : Ws0;
    float* out        = second ? out1 : out0;
    int lc = lcnt[second ? li1 : li0];
    if (lc > n) lc = n;

    for (int t = tid; t < 9 * WROW / 4; t += 256) {
        int k = t / (WROW / 4);
        int r = t % (WROW / 4);
        ((float4*)&Wl[k * WPAD])[r] = ((const float4*)Ws)[t];
    }
    __syncthreads();

    int ib = second ? (int)blockIdx.x - nblkB : (int)blockIdx.x;
    const float inv = 1.0f / NEGS;
    for (int idx = ib * 256 + tid; idx < lc; idx += nblkB * 256) {
        int le = list[idx];
        int i = le & 0xFFFFFF;
        int cn = le >> 24;
        if ((unsigned)i >= (unsigned)n) continue;
        float acc[COUT];
        const float4* orow = (const float4*)(out + (size_t)i * COUT);
#pragma unroll
        for (int c4 = 0; c4 < COUT / 4; ++c4) {
            float4 a = orow[c4];
            acc[c4 * 4 + 0] = (a.x >= 0.f) ? a.x : inv * a.x;
            acc[c4 * 4 + 1] = (a.y >= 0.f) ? a.y : inv * a.y;
            acc[c4 * 4 + 2] = (a.z >= 0.f) ? a.z : inv * a.z;
            acc[c4 * 4 + 3] = (a.w >= 0.f) ? a.w : inv * a.w;
        }
#pragma unroll 1
        for (int m = 0; m < cn; ++m) {
            int e = ent[(size_t)m * n + i];
            int k = e >> 24;
            int j = e & 0xFFFFFF;
            const float4* g4 = (const float4*)(in + (size_t)j * CI);
            const float* wk = &Wl[k * WPAD];
#pragma unroll
            for (int q = 0; q < CI / 4; ++q) {
                float4 v = g4[q];
#pragma unroll
                for (int e4 = 0; e4 < 4; ++e4) {
                    float fe = (e4 == 0) ? v.x : (e4 == 1) ? v.y : (e4 == 2) ? v.z : v.w;
                    const float4* wr = (const float4*)(wk + (q * 4 + e4) * COUT);
#pragma unroll
                    for (int c4 = 0; c4 < COUT / 4; ++c4) {
                        float4 w = wr[c4];
                        acc[c4 * 4 + 0] += fe * w.x;
                        acc[c4 * 4 + 1] += fe * w.y;
                        acc[c4 * 4 + 2] += fe * w.z;
                        acc[c4 * 4 + 3] += fe * w.w;
                    }
                }
            }
        }
        float4* o = (float4*)(out + (size_t)i * COUT);
#pragma unroll
        for (int c4 = 0; c4 < COUT / 4; ++c4) {
            float4 r;
            float y0 = acc[4 * c4 + 0], y1 = acc[4 * c4 + 1];
            float y2 = acc[4 * c4 + 2], y3 = acc[4 * c4 + 3];
            r.x = (y0 >= 0.f) ? y0 : NEGS * y0;
            r.y = (y1 >= 0.f) ? y1 : NEGS * y1;
            r.z = (y2 >= 0.f) ? y2 : NEGS * y2;
            r.w = (y3 >= 0.f) ? y3 : NEGS * y3;
            o[c4] = r;
        }
    }
}

__global__ __launch_bounds__(256) void add_res(float* __restrict__ out,
                                               const float* __restrict__ s, int n4) {
    int i = blockIdx.x * 256 + threadIdx.x;
    if (i < n4) {
        float4 a = ((const float4*)out)[i];
        float4 b = ((const float4*)s)[i];
        a.x += b.x; a.y += b.y; a.z += b.z; a.w += b.w;
        ((float4*)out)[i] = a;
    }
}

extern "C" void kernel_launch(void* const* d_in, const int* in_sizes, int n_in,
                              void* d_out, int out_size, void* d_ws, size_t ws_size,
                              hipStream_t stream) {
    const float* feats = (const float*)d_in[0];
    const int* coords  = (const int*)d_in[1];
    const float* W1    = (const float*)d_in[2];
    const float* W2    = (const float*)d_in[3];
    const float* W3    = (const float*)d_in[4];
    const float* W4    = (const float*)d_in[5];
    const float* gamma = (const float*)d_in[6];
    const float* beta  = (const float*)d_in[7];
    const float* mean  = (const float*)d_in[8];
    const float* var   = (const float*)d_in[9];

    int n = in_sizes[0] / CIN;  // 200000

    char* ws = (char*)d_ws;
    size_t listBytes = (size_t)n * sizeof(int);
    size_t entBytes  = (size_t)8 * n * sizeof(int);
    size_t wsBytes   = (size_t)27648 * sizeof(float);
    size_t shBytes   = (size_t)128 * sizeof(float);
    size_t featBytes = (size_t)n * COUT * sizeof(float);
    size_t gridBytes = (size_t)NCELLS * sizeof(int);

    char* p = ws;
    int* list133 = (int*)p; p += listBytes;
    int* list313 = (int*)p; p += listBytes;
    int* ent133  = (int*)p; p += entBytes;
    int* ent313  = (int*)p; p += entBytes;
    float* Wsc   = (float*)p; p += wsBytes;
    float* shv   = (float*)p; p += shBytes;
    int* lcnt    = (int*)p; p += 16;
    char* fbase = p;
    float* s1 = (float*)fbase;                      // conv1 out
    float* s2 = (float*)(fbase + featBytes);        // shortcut
    float* r1 = (float*)(fbase + 2 * featBytes);    // conv3 out
    int* grid = (int*)fbase;  // overlaps s1/s2; grid dead before they're written

    int nblk = (n + 255) / 256;
    int nblkC = (NCELLS + 255) / 256;
    const int nblkB = 128;  // per side; grid-stride covers list remainder

    prep_weights<<<(27648 + 255) / 256, 256, 0, stream>>>(
        W1, W2, W3, W4, gamma, beta, mean, var, Wsc, shv, lcnt);
    hipMemsetAsync(grid, 0xFF, gridBytes, stream);
    scatter_grid<<<nblk, 256, 0, stream>>>(coords, grid, n);
    build_nbr_cells<<<nblkC, 256, 0, stream>>>(grid,
        ent133, list133, ent313, list313, lcnt, n);

    const float* Wc1 = Wsc + 0     + 4 * CIN * COUT;
    const float* Wc2 = Wsc + 4608  + 4 * COUT * COUT;
    const float* Wc3 = Wsc + 13824 + 4 * CIN * COUT;
    const float* Wc4 = Wsc + 18432 + 4 * COUT * COUT;

    // A13: conv1 center (feats->s1) || conv3 center (feats->r1)
    center_pair<CIN><<<2 * nblk, 256, 0, stream>>>(
        feats, Wc1, shv + 0 * COUT, s1,
        feats, Wc3, shv + 2 * COUT, r1, n, nblk);
    // B13: fix conv1 (list133 -> lcnt[0]) || fix conv3 (list313 -> lcnt[1])
    fix_pair<CIN><<<2 * nblkB, 256, 0, stream>>>(
        feats, list133, ent133, Wsc + 0,     s1,
        feats, list313, ent313, Wsc + 13824, r1, lcnt, 0, 1, n, nblkB);

    // A24: conv2 center (s1->s2) || conv4 center (r1->d_out)
    center_pair<COUT><<<2 * nblk, 256, 0, stream>>>(
        s1, Wc2, shv + 1 * COUT, s2,
        r1, Wc4, shv + 3 * COUT, (float*)d_out, n, nblk);
    // B24: fix conv2 (list313 -> lcnt[1]) || fix conv4 (list133 -> lcnt[0])
    fix_pair<COUT><<<2 * nblkB, 256, 0, stream>>>(
        s1, list313, ent313, Wsc + 4608,  s2,
        r1, list133, ent133, Wsc + 18432, (float*)d_out, lcnt, 1, 0, n, nblkB);

    // d_out += s2 (resA + shortcut)
    int n4 = n * COUT / 4;
    add_res<<<(n4 + 255) / 256, 256, 0, stream>>>((float*)d_out, s2, n4);
}